// Round 6
// baseline (1535.563 us; speedup 1.0000x reference)
//
#include <hip/hip_runtime.h>
#include <hip/hip_bf16.h>
#include <math.h>

#define NNODES 100000
#define NEDGES 3200000
constexpr int NCHB = (NNODES + 255) / 256; // 391 buckets of 256 nodes

typedef __hip_bfloat16 bf16;
__device__ __forceinline__ bf16 f2b(float v) { return __float2bfloat16(v); }
__device__ __forceinline__ float lo2f(unsigned u) { return __uint_as_float(u << 16); }
__device__ __forceinline__ float hi2f(unsigned u) { return __uint_as_float(u & 0xffff0000u); }

// 8-way compile-time-tree select: returns a[c], c in 0..7
__device__ __forceinline__ float sel8(int c, float a0, float a1, float a2, float a3,
                                      float a4, float a5, float a6, float a7) {
    float b0 = (c & 1) ? a1 : a0, b2 = (c & 1) ? a3 : a2;
    float b4 = (c & 1) ? a5 : a4, b6 = (c & 1) ? a7 : a6;
    float c0 = (c & 2) ? b2 : b0, c4 = (c & 2) ? b6 : b4;
    return (c & 4) ? c4 : c0;
}

// ---------------- CSR build (bucketed, write-local) ----------------

// per-block LDS histogram of bucket (dst>>8) counts -> global bs
__global__ __launch_bounds__(256) void k_hist(const int4* __restrict__ dst4,
                                              int* __restrict__ bs) {
    __shared__ int h[NCHB];
    int tid = threadIdx.x;
    for (int i = tid; i < NCHB; i += 256) h[i] = 0;
    __syncthreads();
    for (int e = blockIdx.x * 256 + tid; e < NEDGES / 4; e += gridDim.x * 256) {
        int4 d = dst4[e];
        atomicAdd(&h[d.x >> 8], 1);
        atomicAdd(&h[d.y >> 8], 1);
        atomicAdd(&h[d.z >> 8], 1);
        atomicAdd(&h[d.w >> 8], 1);
    }
    __syncthreads();
    for (int i = tid; i < NCHB; i += 256) {
        int v = h[i];
        if (v) atomicAdd(&bs[i], v);
    }
}

// exclusive scan of the 391 bucket sums (single block) + sentinels
__global__ void k_scanbs(const int* __restrict__ bs, int* __restrict__ bse,
                         int* __restrict__ offs) {
    __shared__ int s[512];
    int i = threadIdx.x;
    int v = (i < NCHB) ? bs[i] : 0;
    s[i] = v;
    __syncthreads();
    for (int off = 1; off < 512; off <<= 1) {
        int t = (i >= off) ? s[i - off] : 0;
        __syncthreads();
        s[i] += t;
        __syncthreads();
    }
    if (i < NCHB) bse[i] = s[i] - v;  // exclusive
    if (i == 0) { bse[NCHB] = NEDGES; offs[NNODES] = NEDGES; }
}

// partition edges into buckets: tmp[bse[b]+pos] = (dst_local<<17)|src
__global__ void k_scatter(const int4* __restrict__ src4, const int4* __restrict__ dst4,
                          const int* __restrict__ bse, int* __restrict__ bcur,
                          int* __restrict__ tmp) {
    int e = blockIdx.x * blockDim.x + threadIdx.x;
    if (e < NEDGES / 4) {
        int4 s = src4[e];
        int4 d = dst4[e];
        int b, p;
        b = d.x >> 8; p = atomicAdd(&bcur[b], 1); tmp[bse[b] + p] = ((d.x & 255) << 17) | s.x;
        b = d.y >> 8; p = atomicAdd(&bcur[b], 1); tmp[bse[b] + p] = ((d.y & 255) << 17) | s.y;
        b = d.z >> 8; p = atomicAdd(&bcur[b], 1); tmp[bse[b] + p] = ((d.z & 255) << 17) | s.z;
        b = d.w >> 8; p = atomicAdd(&bcur[b], 1); tmp[bse[b] + p] = ((d.w & 255) << 17) | s.w;
    }
}

// per-bucket: count -> LDS scan (writes offs+deginv) -> local fill of contiguous csr slice
__global__ __launch_bounds__(256) void k_bucket(const int* __restrict__ tmp,
                                                const int* __restrict__ bse,
                                                int* __restrict__ offs,
                                                float* __restrict__ deginv,
                                                int* __restrict__ csr) {
    int b = blockIdx.x, tid = threadIdx.x;
    int lane = tid & 63, wid = tid >> 6;
    __shared__ int cnt[256], soff[256], ws[4];
    cnt[tid] = 0;
    __syncthreads();
    int s0 = bse[b], s1 = bse[b + 1];
    for (int i = s0 + tid; i < s1; i += 256) atomicAdd(&cnt[tmp[i] >> 17], 1);
    __syncthreads();
    int d = cnt[tid];
    int v = d;  // inclusive wave scan
    { int t = __shfl_up(v, 1);  if (lane >= 1)  v += t; }
    { int t = __shfl_up(v, 2);  if (lane >= 2)  v += t; }
    { int t = __shfl_up(v, 4);  if (lane >= 4)  v += t; }
    { int t = __shfl_up(v, 8);  if (lane >= 8)  v += t; }
    { int t = __shfl_up(v, 16); if (lane >= 16) v += t; }
    { int t = __shfl_up(v, 32); if (lane >= 32) v += t; }
    if (lane == 63) ws[wid] = v;
    __syncthreads();
    int woff = 0;
#pragma unroll
    for (int i = 0; i < 4; i++) woff += (i < wid) ? ws[i] : 0;
    int excl = woff + v - d;
    soff[tid] = excl;
    int node = b * 256 + tid;
    if (node < NNODES) {
        offs[node] = s0 + excl;
        deginv[node] = 1.0f / (float)max(d, 1);
    }
    cnt[tid] = 0;
    __syncthreads();
    for (int i = s0 + tid; i < s1; i += 256) {
        int e = tmp[i];
        int dl = e >> 17, src = e & 0x1FFFF;
        int slot = atomicAdd(&cnt[dl], 1);
        csr[s0 + soff[dl] + slot] = src;
    }
}

// ---- Layer 1 (persistent, weights in VGPRs): gather x -> h1 regs -> t2 bf16, r2 fp32 ----

__global__ __launch_bounds__(256) void k_layer1(
    const float* __restrict__ x, const int* __restrict__ csr,
    const int* __restrict__ offs, const float* __restrict__ deginv,
    const float* __restrict__ w1l, const float* __restrict__ w1r,
    const float* __restrict__ b1,
    const float* __restrict__ g1, const float* __restrict__ bb1,
    const float* __restrict__ m1, const float* __restrict__ v1,
    const float* __restrict__ w2l, const float* __restrict__ w2r,
    const float* __restrict__ b2,
    const float* __restrict__ g2, const float* __restrict__ bb2,
    const float* __restrict__ m2, const float* __restrict__ v2,
    bf16* __restrict__ t2, float* __restrict__ r2)
{
    int tid = threadIdx.x;
    int lane = tid & 63, wid = tid >> 6;

    float k1 = g1[lane] * rsqrtf(v1[lane] + 1e-5f);
    float k2 = g2[lane] * rsqrtf(v2[lane] + 1e-5f);
    float c1 = (b1[lane] - m1[lane]) * k1 + bb1[lane];
    float c2 = (b2[lane] - m2[lane]) * k2 + bb2[lane];
    float w1lr[8], w1rr[8];
#pragma unroll
    for (int k = 0; k < 8; k++) {
        w1lr[k] = w1l[k * 64 + lane] * k1;
        w1rr[k] = w1r[k * 64 + lane] * k1;
    }
    float w2lr[64], w2rr[64];
#pragma unroll
    for (int k = 0; k < 64; k++) {
        w2lr[k] = w2l[k * 64 + lane] * k2;
        w2rr[k] = w2r[k * 64 + lane] * k2;
    }

    const float4* xv = (const float4*)x;
    for (int base = blockIdx.x * 4; base < NNODES; base += gridDim.x * 4) {
        int node = base + wid;
        if (node >= NNODES) continue;

        int start = offs[node];
        int d = offs[node + 1] - start;
        int dl = min(d, 64);
        int c = csr[start + lane];                 // csr padded +64
        float xs = x[node * 8 + (lane & 7)];

        int fh = lane & 1;
        int g  = lane >> 1;
        int i0 = g, i1 = g + 32;
        int s0 = __shfl(c, i0), s1 = __shfl(c, i1);
        float m0 = (i0 < dl) ? 1.f : 0.f;
        float m1f = (i1 < dl) ? 1.f : 0.f;
        s0 = (i0 < dl) ? s0 : 0;
        s1 = (i1 < dl) ? s1 : 0;
        float4 w0 = xv[(size_t)s0 * 2 + fh];
        float4 w1 = xv[(size_t)s1 * 2 + fh];
        float ax = m0 * w0.x + m1f * w1.x;
        float ay = m0 * w0.y + m1f * w1.y;
        float az = m0 * w0.z + m1f * w1.z;
        float aw = m0 * w0.w + m1f * w1.w;
        for (int i = g + 64; i < d; i += 32) {     // rare tail
            int s = csr[start + i];
            float4 w = xv[(size_t)s * 2 + fh];
            ax += w.x; ay += w.y; az += w.z; aw += w.w;
        }
#define RED1(X) X += __shfl_xor(X, 2); X += __shfl_xor(X, 4); X += __shfl_xor(X, 8); \
                X += __shfl_xor(X, 16); X += __shfl_xor(X, 32);
        RED1(ax) RED1(ay) RED1(az) RED1(aw)
#undef RED1
        float di = deginv[node];
        ax *= di; ay *= di; az *= di; aw *= di;

        float h = c1;
#pragma unroll
        for (int k = 0; k < 8; k++) {
            float comp = ((k & 3) == 0) ? ax : ((k & 3) == 1) ? ay : ((k & 3) == 2) ? az : aw;
            float a  = __shfl(comp, k >> 2);
            float xr = __shfl(xs, k);
            h = fmaf(a, w1lr[k], fmaf(xr, w1rr[k], h));
        }
        h = fmaxf(h, 0.f);

        float tt = 0.f, rr = c2;
#pragma unroll
        for (int k = 0; k < 64; k++) {
            float hv = __shfl(h, k);
            tt = fmaf(hv, w2lr[k], tt);
            rr = fmaf(hv, w2rr[k], rr);
        }
        t2[(size_t)node * 64 + lane] = f2b(tt);
        r2[(size_t)node * 64 + lane] = rr;
    }
}

// ---- Layer 2 (persistent, w3 cols in VGPRs): gather t2 -> h2 regs -> t3 bf16, r3 fp32 ----

__global__ __launch_bounds__(256) void k_layer2(
    const bf16* __restrict__ t2, const float* __restrict__ r2,
    const int* __restrict__ csr, const int* __restrict__ offs,
    const float* __restrict__ deginv,
    const float* __restrict__ w3l, const float* __restrict__ w3r,
    const float* __restrict__ b3,
    bf16* __restrict__ t3, float* __restrict__ r3)
{
    int tid = threadIdx.x;
    int lane = tid & 63, wid = tid >> 6;
    int j = lane & 31, half = lane >> 5;

    const float* wp = half ? w3r : w3l;
    float wcol[64];
#pragma unroll
    for (int k = 0; k < 64; k++) wcol[k] = wp[k * 32 + j];
    float b3v = half ? b3[j] : 0.f;

    const uint4* t2v = (const uint4*)t2;
    for (int base = blockIdx.x * 4; base < NNODES; base += gridDim.x * 4) {
        int node = base + wid;
        if (node >= NNODES) continue;

        int start = offs[node];
        int d = offs[node + 1] - start;
        int dl = min(d, 64);
        int c = csr[start + lane];
        float r2v = r2[(size_t)node * 64 + lane];

        int fq = lane & 7;
        int g  = lane >> 3;
        int   si[8];
        float mk[8];
#pragma unroll
        for (int t = 0; t < 8; t++) {
            int i = g + 8 * t;
            int s = __shfl(c, i);
            mk[t] = (i < dl) ? 1.f : 0.f;
            si[t] = (i < dl) ? s : 0;
        }
        uint4 w0 = t2v[(size_t)si[0] * 8 + fq];
        uint4 w1 = t2v[(size_t)si[1] * 8 + fq];
        uint4 w2 = t2v[(size_t)si[2] * 8 + fq];
        uint4 w3 = t2v[(size_t)si[3] * 8 + fq];
        uint4 w4 = t2v[(size_t)si[4] * 8 + fq];
        uint4 w5 = t2v[(size_t)si[5] * 8 + fq];
        uint4 w6 = t2v[(size_t)si[6] * 8 + fq];
        uint4 w7 = t2v[(size_t)si[7] * 8 + fq];

        float a0 = 0, a1 = 0, a2 = 0, a3 = 0, a4 = 0, a5 = 0, a6 = 0, a7 = 0;
#define CONS(W, M) \
        a0 = fmaf(M, lo2f(W.x), a0); a1 = fmaf(M, hi2f(W.x), a1); \
        a2 = fmaf(M, lo2f(W.y), a2); a3 = fmaf(M, hi2f(W.y), a3); \
        a4 = fmaf(M, lo2f(W.z), a4); a5 = fmaf(M, hi2f(W.z), a5); \
        a6 = fmaf(M, lo2f(W.w), a6); a7 = fmaf(M, hi2f(W.w), a7);
        CONS(w0, mk[0]) CONS(w1, mk[1]) CONS(w2, mk[2]) CONS(w3, mk[3])
        CONS(w4, mk[4]) CONS(w5, mk[5]) CONS(w6, mk[6]) CONS(w7, mk[7])
        for (int i = g + 64; i < d; i += 8) {
            int s = csr[start + i];
            uint4 w = t2v[(size_t)s * 8 + fq];
            CONS(w, 1.f)
        }
#undef CONS
#define RED2(X) X += __shfl_xor(X, 8); X += __shfl_xor(X, 16); X += __shfl_xor(X, 32);
        RED2(a0) RED2(a1) RED2(a2) RED2(a3) RED2(a4) RED2(a5) RED2(a6) RED2(a7)
#undef RED2
        float u = sel8(lane >> 3, a0, a1, a2, a3, a4, a5, a6, a7);
        int srcl = ((lane & 7) << 3) | (lane >> 3);
        float v = __shfl(u, srcl);

        float h2 = fmaxf(v * deginv[node] + r2v, 0.f);

        float acc = b3v;
#pragma unroll
        for (int k = 0; k < 64; k++) {
            float hv = __shfl(h2, k);
            acc = fmaf(hv, wcol[k], acc);
        }
        if (half == 0) t3[(size_t)node * 32 + j] = f2b(acc);
        else           r3[(size_t)node * 32 + j] = acc;
    }
}

// ---- Layer 3: gather t3 (bf16) -> relu(agg+r3) -> fc -> sigmoid ----

__global__ __launch_bounds__(256) void k_layer3(
    const bf16* __restrict__ t3, const float* __restrict__ r3,
    const int* __restrict__ csr, const int* __restrict__ offs,
    const float* __restrict__ deginv,
    const float* __restrict__ fcw, const float* __restrict__ fcb,
    float* __restrict__ out)
{
    int tid = threadIdx.x;
    int lane = tid & 63;
    int node = blockIdx.x * 4 + (tid >> 6);
    if (node >= NNODES) return;

    int o = lane & 31;
    float fcwv = fcw[o];
    float fcbv = fcb[0];

    int start = offs[node];
    int d = offs[node + 1] - start;
    int dl = min(d, 64);
    int c = csr[start + lane];
    float r3v = r3[(size_t)node * 32 + o];

    int fq = lane & 3;
    int g  = lane >> 2;
    const uint4* t3v = (const uint4*)t3;

    int   si[4];
    float mk[4];
#pragma unroll
    for (int t = 0; t < 4; t++) {
        int i = g + 16 * t;
        int s = __shfl(c, i);
        mk[t] = (i < dl) ? 1.f : 0.f;
        si[t] = (i < dl) ? s : 0;
    }
    uint4 w0 = t3v[(size_t)si[0] * 4 + fq];
    uint4 w1 = t3v[(size_t)si[1] * 4 + fq];
    uint4 w2 = t3v[(size_t)si[2] * 4 + fq];
    uint4 w3 = t3v[(size_t)si[3] * 4 + fq];

    float a0 = 0, a1 = 0, a2 = 0, a3 = 0, a4 = 0, a5 = 0, a6 = 0, a7 = 0;
#define CONS(W, M) \
    a0 = fmaf(M, lo2f(W.x), a0); a1 = fmaf(M, hi2f(W.x), a1); \
    a2 = fmaf(M, lo2f(W.y), a2); a3 = fmaf(M, hi2f(W.y), a3); \
    a4 = fmaf(M, lo2f(W.z), a4); a5 = fmaf(M, hi2f(W.z), a5); \
    a6 = fmaf(M, lo2f(W.w), a6); a7 = fmaf(M, hi2f(W.w), a7);
    CONS(w0, mk[0]) CONS(w1, mk[1]) CONS(w2, mk[2]) CONS(w3, mk[3])
    for (int i = g + 64; i < d; i += 16) {
        int s = csr[start + i];
        uint4 w = t3v[(size_t)s * 4 + fq];
        CONS(w, 1.f)
    }
#undef CONS
#define RED3(X) X += __shfl_xor(X, 4); X += __shfl_xor(X, 8); X += __shfl_xor(X, 16); X += __shfl_xor(X, 32);
    RED3(a0) RED3(a1) RED3(a2) RED3(a3) RED3(a4) RED3(a5) RED3(a6) RED3(a7)
#undef RED3
    float u = sel8((lane >> 2) & 7, a0, a1, a2, a3, a4, a5, a6, a7);
    int srcl = ((lane & 7) << 2) | ((lane >> 3) & 3);
    float v = __shfl(u, srcl);

    float h3 = fmaxf(v * deginv[node] + r3v, 0.f);

    float p = h3 * fcwv;
    p += __shfl_xor(p, 1);
    p += __shfl_xor(p, 2);
    p += __shfl_xor(p, 4);
    p += __shfl_xor(p, 8);
    p += __shfl_xor(p, 16);
    if (lane == 0) {
        float z = p + fcbv;
        out[node] = 1.0f / (1.0f + expf(-z));
    }
}

// ---------------- launch ----------------

extern "C" void kernel_launch(void* const* d_in, const int* in_sizes, int n_in,
                              void* d_out, int out_size, void* d_ws, size_t ws_size,
                              hipStream_t stream)
{
    const float* x   = (const float*)d_in[0];
    const int*   ei  = (const int*)d_in[1];
    const int*   src = ei;
    const int*   dst = ei + NEDGES;
    const float* w1l = (const float*)d_in[2];
    const float* w1r = (const float*)d_in[3];
    const float* b1  = (const float*)d_in[4];
    const float* g1  = (const float*)d_in[5];
    const float* bb1 = (const float*)d_in[6];
    const float* m1  = (const float*)d_in[7];
    const float* v1  = (const float*)d_in[8];
    const float* w2l = (const float*)d_in[9];
    const float* w2r = (const float*)d_in[10];
    const float* b2  = (const float*)d_in[11];
    const float* g2  = (const float*)d_in[12];
    const float* bb2 = (const float*)d_in[13];
    const float* m2  = (const float*)d_in[14];
    const float* v2  = (const float*)d_in[15];
    const float* w3l = (const float*)d_in[16];
    const float* w3r = (const float*)d_in[17];
    const float* b3  = (const float*)d_in[18];
    const float* fcw = (const float*)d_in[19];
    const float* fcb = (const float*)d_in[20];

    char* ws = (char*)d_ws;
    size_t off = 0;
    auto alloc = [&](size_t bytes) -> void* {
        void* p = ws + off;
        off += (bytes + 255) & ~(size_t)255;
        return p;
    };
    int*   offs   = (int*)alloc((size_t)(NNODES + 1) * 4);
    int*   bs     = (int*)alloc((size_t)NCHB * 4);
    int*   bse    = (int*)alloc((size_t)(NCHB + 1) * 4);
    int*   bcur   = (int*)alloc((size_t)NCHB * 4);
    float* deginv = (float*)alloc((size_t)NNODES * 4);
    int*   csr    = (int*)alloc((size_t)(NEDGES + 64) * 4);  // +64 pad
    bf16*  t2     = (bf16*)alloc((size_t)NNODES * 64 * 2);
    float* r2     = (float*)alloc((size_t)NNODES * 64 * 4);
    bf16*  t3     = (bf16*)alloc((size_t)NNODES * 32 * 2);
    float* r3     = (float*)alloc((size_t)NNODES * 32 * 4);
    int*   tmp    = (int*)r2;   // aliased: consumed by k_bucket before layer1 writes r2

    hipMemsetAsync(bs, 0, (size_t)NCHB * 4, stream);
    hipMemsetAsync(bcur, 0, (size_t)NCHB * 4, stream);

    k_hist<<<782, 256, 0, stream>>>((const int4*)dst, bs);
    k_scanbs<<<1, 512, 0, stream>>>(bs, bse, offs);
    k_scatter<<<(NEDGES / 4 + 255) / 256, 256, 0, stream>>>((const int4*)src, (const int4*)dst,
                                                            bse, bcur, tmp);
    k_bucket<<<NCHB, 256, 0, stream>>>(tmp, bse, offs, deginv, csr);

    k_layer1<<<768, 256, 0, stream>>>(x, csr, offs, deginv,
                                      w1l, w1r, b1, g1, bb1, m1, v1,
                                      w2l, w2r, b2, g2, bb2, m2, v2,
                                      t2, r2);
    k_layer2<<<1024, 256, 0, stream>>>(t2, r2, csr, offs, deginv,
                                       w3l, w3r, b3, t3, r3);
    k_layer3<<<(NNODES + 3) / 4, 256, 0, stream>>>(t3, r3, csr, offs, deginv,
                                                   fcw, fcb, (float*)d_out);
}

// Round 7
// 426.647 us; speedup vs baseline: 3.5991x; 3.5991x over previous
//
#include <hip/hip_runtime.h>
#include <hip/hip_bf16.h>
#include <math.h>

#define NNODES 100000
#define NEDGES 3200000
constexpr int NCHB = (NNODES + 255) / 256; // 391 buckets of 256 nodes
constexpr int NBLK = 256;                  // partition blocks
constexpr int Q4PB = (NEDGES / 4) / NBLK;  // 3125 int4 per block (exact)

typedef __hip_bfloat16 bf16;
__device__ __forceinline__ bf16 f2b(float v) { return __float2bfloat16(v); }
__device__ __forceinline__ float lo2f(unsigned u) { return __uint_as_float(u << 16); }
__device__ __forceinline__ float hi2f(unsigned u) { return __uint_as_float(u & 0xffff0000u); }

// 8-way compile-time-tree select: returns a[c], c in 0..7
__device__ __forceinline__ float sel8(int c, float a0, float a1, float a2, float a3,
                                      float a4, float a5, float a6, float a7) {
    float b0 = (c & 1) ? a1 : a0, b2 = (c & 1) ? a3 : a2;
    float b4 = (c & 1) ? a5 : a4, b6 = (c & 1) ? a7 : a6;
    float c0 = (c & 2) ? b2 : b0, c4 = (c & 2) ? b6 : b4;
    return (c & 4) ? c4 : c0;
}

// ---------------- CSR build: one-pass radix partition by dst>>8 ----------------

// per-block LDS histogram -> histT[bin][blk]; bin totals via fire-and-forget atomics
__global__ __launch_bounds__(256) void k_hist2(const int4* __restrict__ dst4,
                                               int* __restrict__ histT,
                                               int* __restrict__ bs) {
    __shared__ int h[NCHB];
    int tid = threadIdx.x, blk = blockIdx.x;
    for (int i = tid; i < NCHB; i += 256) h[i] = 0;
    __syncthreads();
    int base = blk * Q4PB;
    for (int i = tid; i < Q4PB; i += 256) {
        int4 d = dst4[base + i];
        atomicAdd(&h[d.x >> 8], 1);
        atomicAdd(&h[d.y >> 8], 1);
        atomicAdd(&h[d.z >> 8], 1);
        atomicAdd(&h[d.w >> 8], 1);
    }
    __syncthreads();
    for (int i = tid; i < NCHB; i += 256) {
        int v = h[i];
        histT[i * NBLK + blk] = v;
        if (v) atomicAdd(&bs[i], v);   // no result needed -> pipelines
    }
}

// exclusive scan of the 391 bucket sums (single block) + sentinels
__global__ void k_scanbs(const int* __restrict__ bs, int* __restrict__ bse,
                         int* __restrict__ offs) {
    __shared__ int s[512];
    int i = threadIdx.x;
    int v = (i < NCHB) ? bs[i] : 0;
    s[i] = v;
    __syncthreads();
    for (int off = 1; off < 512; off <<= 1) {
        int t = (i >= off) ? s[i - off] : 0;
        __syncthreads();
        s[i] += t;
        __syncthreads();
    }
    if (i < NCHB) bse[i] = s[i] - v;  // exclusive
    if (i == 0) { bse[NCHB] = NEDGES; offs[NNODES] = NEDGES; }
}

// per-bin: exclusive scan of the 256 per-block counts, + bse[bin] -> global bases in-place
__global__ __launch_bounds__(256) void k_scanhist(int* __restrict__ histT,
                                                  const int* __restrict__ bse) {
    int b = blockIdx.x, tid = threadIdx.x;
    int lane = tid & 63, wid = tid >> 6;
    int d = histT[b * NBLK + tid];
    int v = d;  // inclusive wave scan
    { int t = __shfl_up(v, 1);  if (lane >= 1)  v += t; }
    { int t = __shfl_up(v, 2);  if (lane >= 2)  v += t; }
    { int t = __shfl_up(v, 4);  if (lane >= 4)  v += t; }
    { int t = __shfl_up(v, 8);  if (lane >= 8)  v += t; }
    { int t = __shfl_up(v, 16); if (lane >= 16) v += t; }
    { int t = __shfl_up(v, 32); if (lane >= 32) v += t; }
    __shared__ int ws[4];
    if (lane == 63) ws[wid] = v;
    __syncthreads();
    int woff = 0;
#pragma unroll
    for (int i = 0; i < 4; i++) woff += (i < wid) ? ws[i] : 0;
    histT[b * NBLK + tid] = bse[b] + woff + v - d;   // exclusive global base
}

// partition: LDS cursors seeded with exact global bases -> no global atomics
__global__ __launch_bounds__(256) void k_scatter2(const int4* __restrict__ src4,
                                                  const int4* __restrict__ dst4,
                                                  const int* __restrict__ histT,
                                                  int* __restrict__ tmp) {
    __shared__ int cur[NCHB];
    int tid = threadIdx.x, blk = blockIdx.x;
    for (int i = tid; i < NCHB; i += 256) cur[i] = histT[i * NBLK + blk];
    __syncthreads();
    int base = blk * Q4PB;
    for (int i = tid; i < Q4PB; i += 256) {
        int4 s = src4[base + i];
        int4 d = dst4[base + i];
        int b, p;
        b = d.x >> 8; p = atomicAdd(&cur[b], 1); tmp[p] = ((d.x & 255) << 17) | s.x;
        b = d.y >> 8; p = atomicAdd(&cur[b], 1); tmp[p] = ((d.y & 255) << 17) | s.y;
        b = d.z >> 8; p = atomicAdd(&cur[b], 1); tmp[p] = ((d.z & 255) << 17) | s.z;
        b = d.w >> 8; p = atomicAdd(&cur[b], 1); tmp[p] = ((d.w & 255) << 17) | s.w;
    }
}

// per-bucket: count -> LDS scan (writes offs+deginv) -> local fill of contiguous csr slice
__global__ __launch_bounds__(256) void k_bucket(const int* __restrict__ tmp,
                                                const int* __restrict__ bse,
                                                int* __restrict__ offs,
                                                float* __restrict__ deginv,
                                                int* __restrict__ csr) {
    int b = blockIdx.x, tid = threadIdx.x;
    int lane = tid & 63, wid = tid >> 6;
    __shared__ int cnt[256], soff[256], ws[4];
    cnt[tid] = 0;
    __syncthreads();
    int s0 = bse[b], s1 = bse[b + 1];
    for (int i = s0 + tid; i < s1; i += 256) atomicAdd(&cnt[tmp[i] >> 17], 1);
    __syncthreads();
    int d = cnt[tid];
    int v = d;  // inclusive wave scan
    { int t = __shfl_up(v, 1);  if (lane >= 1)  v += t; }
    { int t = __shfl_up(v, 2);  if (lane >= 2)  v += t; }
    { int t = __shfl_up(v, 4);  if (lane >= 4)  v += t; }
    { int t = __shfl_up(v, 8);  if (lane >= 8)  v += t; }
    { int t = __shfl_up(v, 16); if (lane >= 16) v += t; }
    { int t = __shfl_up(v, 32); if (lane >= 32) v += t; }
    if (lane == 63) ws[wid] = v;
    __syncthreads();
    int woff = 0;
#pragma unroll
    for (int i = 0; i < 4; i++) woff += (i < wid) ? ws[i] : 0;
    int excl = woff + v - d;
    soff[tid] = excl;
    int node = b * 256 + tid;
    if (node < NNODES) {
        offs[node] = s0 + excl;
        deginv[node] = 1.0f / (float)max(d, 1);
    }
    cnt[tid] = 0;
    __syncthreads();
    for (int i = s0 + tid; i < s1; i += 256) {
        int e = tmp[i];
        int dl = e >> 17, src = e & 0x1FFFF;
        int slot = atomicAdd(&cnt[dl], 1);
        csr[s0 + soff[dl] + slot] = src;
    }
}

// ---- Layer 1 (persistent, weights in VGPRs): gather x -> h1 regs -> t2 bf16, r2 fp32 ----

__global__ __launch_bounds__(256) void k_layer1(
    const float* __restrict__ x, const int* __restrict__ csr,
    const int* __restrict__ offs, const float* __restrict__ deginv,
    const float* __restrict__ w1l, const float* __restrict__ w1r,
    const float* __restrict__ b1,
    const float* __restrict__ g1, const float* __restrict__ bb1,
    const float* __restrict__ m1, const float* __restrict__ v1,
    const float* __restrict__ w2l, const float* __restrict__ w2r,
    const float* __restrict__ b2,
    const float* __restrict__ g2, const float* __restrict__ bb2,
    const float* __restrict__ m2, const float* __restrict__ v2,
    bf16* __restrict__ t2, float* __restrict__ r2)
{
    int tid = threadIdx.x;
    int lane = tid & 63, wid = tid >> 6;

    float k1 = g1[lane] * rsqrtf(v1[lane] + 1e-5f);
    float k2 = g2[lane] * rsqrtf(v2[lane] + 1e-5f);
    float c1 = (b1[lane] - m1[lane]) * k1 + bb1[lane];
    float c2 = (b2[lane] - m2[lane]) * k2 + bb2[lane];
    float w1lr[8], w1rr[8];
#pragma unroll
    for (int k = 0; k < 8; k++) {
        w1lr[k] = w1l[k * 64 + lane] * k1;
        w1rr[k] = w1r[k * 64 + lane] * k1;
    }
    float w2lr[64], w2rr[64];
#pragma unroll
    for (int k = 0; k < 64; k++) {
        w2lr[k] = w2l[k * 64 + lane] * k2;
        w2rr[k] = w2r[k * 64 + lane] * k2;
    }

    const float4* xv = (const float4*)x;
    for (int base = blockIdx.x * 4; base < NNODES; base += gridDim.x * 4) {
        int node = base + wid;
        if (node >= NNODES) continue;

        int start = offs[node];
        int d = offs[node + 1] - start;
        int dl = min(d, 64);
        int c = csr[start + lane];                 // csr padded +64
        float xs = x[node * 8 + (lane & 7)];

        int fh = lane & 1;
        int g  = lane >> 1;
        int i0 = g, i1 = g + 32;
        int s0 = __shfl(c, i0), s1 = __shfl(c, i1);
        float m0 = (i0 < dl) ? 1.f : 0.f;
        float m1f = (i1 < dl) ? 1.f : 0.f;
        s0 = (i0 < dl) ? s0 : 0;
        s1 = (i1 < dl) ? s1 : 0;
        float4 w0 = xv[(size_t)s0 * 2 + fh];
        float4 w1 = xv[(size_t)s1 * 2 + fh];
        float ax = m0 * w0.x + m1f * w1.x;
        float ay = m0 * w0.y + m1f * w1.y;
        float az = m0 * w0.z + m1f * w1.z;
        float aw = m0 * w0.w + m1f * w1.w;
        for (int i = g + 64; i < d; i += 32) {     // rare tail
            int s = csr[start + i];
            float4 w = xv[(size_t)s * 2 + fh];
            ax += w.x; ay += w.y; az += w.z; aw += w.w;
        }
#define RED1(X) X += __shfl_xor(X, 2); X += __shfl_xor(X, 4); X += __shfl_xor(X, 8); \
                X += __shfl_xor(X, 16); X += __shfl_xor(X, 32);
        RED1(ax) RED1(ay) RED1(az) RED1(aw)
#undef RED1
        float di = deginv[node];
        ax *= di; ay *= di; az *= di; aw *= di;

        float h = c1;
#pragma unroll
        for (int k = 0; k < 8; k++) {
            float comp = ((k & 3) == 0) ? ax : ((k & 3) == 1) ? ay : ((k & 3) == 2) ? az : aw;
            float a  = __shfl(comp, k >> 2);
            float xr = __shfl(xs, k);
            h = fmaf(a, w1lr[k], fmaf(xr, w1rr[k], h));
        }
        h = fmaxf(h, 0.f);

        float tt = 0.f, rr = c2;
#pragma unroll
        for (int k = 0; k < 64; k++) {
            float hv = __shfl(h, k);
            tt = fmaf(hv, w2lr[k], tt);
            rr = fmaf(hv, w2rr[k], rr);
        }
        t2[(size_t)node * 64 + lane] = f2b(tt);
        r2[(size_t)node * 64 + lane] = rr;
    }
}

// ---- Layer 2 (persistent, w3 cols in VGPRs): gather t2 -> h2 regs -> t3 bf16, r3 fp32 ----

__global__ __launch_bounds__(256) void k_layer2(
    const bf16* __restrict__ t2, const float* __restrict__ r2,
    const int* __restrict__ csr, const int* __restrict__ offs,
    const float* __restrict__ deginv,
    const float* __restrict__ w3l, const float* __restrict__ w3r,
    const float* __restrict__ b3,
    bf16* __restrict__ t3, float* __restrict__ r3)
{
    int tid = threadIdx.x;
    int lane = tid & 63, wid = tid >> 6;
    int j = lane & 31, half = lane >> 5;

    const float* wp = half ? w3r : w3l;
    float wcol[64];
#pragma unroll
    for (int k = 0; k < 64; k++) wcol[k] = wp[k * 32 + j];
    float b3v = half ? b3[j] : 0.f;

    const uint4* t2v = (const uint4*)t2;
    for (int base = blockIdx.x * 4; base < NNODES; base += gridDim.x * 4) {
        int node = base + wid;
        if (node >= NNODES) continue;

        int start = offs[node];
        int d = offs[node + 1] - start;
        int dl = min(d, 64);
        int c = csr[start + lane];
        float r2v = r2[(size_t)node * 64 + lane];

        int fq = lane & 7;
        int g  = lane >> 3;
        int   si[8];
        float mk[8];
#pragma unroll
        for (int t = 0; t < 8; t++) {
            int i = g + 8 * t;
            int s = __shfl(c, i);
            mk[t] = (i < dl) ? 1.f : 0.f;
            si[t] = (i < dl) ? s : 0;
        }
        uint4 w0 = t2v[(size_t)si[0] * 8 + fq];
        uint4 w1 = t2v[(size_t)si[1] * 8 + fq];
        uint4 w2 = t2v[(size_t)si[2] * 8 + fq];
        uint4 w3 = t2v[(size_t)si[3] * 8 + fq];
        uint4 w4 = t2v[(size_t)si[4] * 8 + fq];
        uint4 w5 = t2v[(size_t)si[5] * 8 + fq];
        uint4 w6 = t2v[(size_t)si[6] * 8 + fq];
        uint4 w7 = t2v[(size_t)si[7] * 8 + fq];

        float a0 = 0, a1 = 0, a2 = 0, a3 = 0, a4 = 0, a5 = 0, a6 = 0, a7 = 0;
#define CONS(W, M) \
        a0 = fmaf(M, lo2f(W.x), a0); a1 = fmaf(M, hi2f(W.x), a1); \
        a2 = fmaf(M, lo2f(W.y), a2); a3 = fmaf(M, hi2f(W.y), a3); \
        a4 = fmaf(M, lo2f(W.z), a4); a5 = fmaf(M, hi2f(W.z), a5); \
        a6 = fmaf(M, lo2f(W.w), a6); a7 = fmaf(M, hi2f(W.w), a7);
        CONS(w0, mk[0]) CONS(w1, mk[1]) CONS(w2, mk[2]) CONS(w3, mk[3])
        CONS(w4, mk[4]) CONS(w5, mk[5]) CONS(w6, mk[6]) CONS(w7, mk[7])
        for (int i = g + 64; i < d; i += 8) {
            int s = csr[start + i];
            uint4 w = t2v[(size_t)s * 8 + fq];
            CONS(w, 1.f)
        }
#undef CONS
#define RED2(X) X += __shfl_xor(X, 8); X += __shfl_xor(X, 16); X += __shfl_xor(X, 32);
        RED2(a0) RED2(a1) RED2(a2) RED2(a3) RED2(a4) RED2(a5) RED2(a6) RED2(a7)
#undef RED2
        float u = sel8(lane >> 3, a0, a1, a2, a3, a4, a5, a6, a7);
        int srcl = ((lane & 7) << 3) | (lane >> 3);
        float v = __shfl(u, srcl);

        float h2 = fmaxf(v * deginv[node] + r2v, 0.f);

        float acc = b3v;
#pragma unroll
        for (int k = 0; k < 64; k++) {
            float hv = __shfl(h2, k);
            acc = fmaf(hv, wcol[k], acc);
        }
        if (half == 0) t3[(size_t)node * 32 + j] = f2b(acc);
        else           r3[(size_t)node * 32 + j] = acc;
    }
}

// ---- Layer 3: gather t3 (bf16) -> relu(agg+r3) -> fc -> sigmoid ----

__global__ __launch_bounds__(256) void k_layer3(
    const bf16* __restrict__ t3, const float* __restrict__ r3,
    const int* __restrict__ csr, const int* __restrict__ offs,
    const float* __restrict__ deginv,
    const float* __restrict__ fcw, const float* __restrict__ fcb,
    float* __restrict__ out)
{
    int tid = threadIdx.x;
    int lane = tid & 63;
    int node = blockIdx.x * 4 + (tid >> 6);
    if (node >= NNODES) return;

    int o = lane & 31;
    float fcwv = fcw[o];
    float fcbv = fcb[0];

    int start = offs[node];
    int d = offs[node + 1] - start;
    int dl = min(d, 64);
    int c = csr[start + lane];
    float r3v = r3[(size_t)node * 32 + o];

    int fq = lane & 3;
    int g  = lane >> 2;
    const uint4* t3v = (const uint4*)t3;

    int   si[4];
    float mk[4];
#pragma unroll
    for (int t = 0; t < 4; t++) {
        int i = g + 16 * t;
        int s = __shfl(c, i);
        mk[t] = (i < dl) ? 1.f : 0.f;
        si[t] = (i < dl) ? s : 0;
    }
    uint4 w0 = t3v[(size_t)si[0] * 4 + fq];
    uint4 w1 = t3v[(size_t)si[1] * 4 + fq];
    uint4 w2 = t3v[(size_t)si[2] * 4 + fq];
    uint4 w3 = t3v[(size_t)si[3] * 4 + fq];

    float a0 = 0, a1 = 0, a2 = 0, a3 = 0, a4 = 0, a5 = 0, a6 = 0, a7 = 0;
#define CONS(W, M) \
    a0 = fmaf(M, lo2f(W.x), a0); a1 = fmaf(M, hi2f(W.x), a1); \
    a2 = fmaf(M, lo2f(W.y), a2); a3 = fmaf(M, hi2f(W.y), a3); \
    a4 = fmaf(M, lo2f(W.z), a4); a5 = fmaf(M, hi2f(W.z), a5); \
    a6 = fmaf(M, lo2f(W.w), a6); a7 = fmaf(M, hi2f(W.w), a7);
    CONS(w0, mk[0]) CONS(w1, mk[1]) CONS(w2, mk[2]) CONS(w3, mk[3])
    for (int i = g + 64; i < d; i += 16) {
        int s = csr[start + i];
        uint4 w = t3v[(size_t)s * 4 + fq];
        CONS(w, 1.f)
    }
#undef CONS
#define RED3(X) X += __shfl_xor(X, 4); X += __shfl_xor(X, 8); X += __shfl_xor(X, 16); X += __shfl_xor(X, 32);
    RED3(a0) RED3(a1) RED3(a2) RED3(a3) RED3(a4) RED3(a5) RED3(a6) RED3(a7)
#undef RED3
    float u = sel8((lane >> 2) & 7, a0, a1, a2, a3, a4, a5, a6, a7);
    int srcl = ((lane & 7) << 2) | ((lane >> 3) & 3);
    float v = __shfl(u, srcl);

    float h3 = fmaxf(v * deginv[node] + r3v, 0.f);

    float p = h3 * fcwv;
    p += __shfl_xor(p, 1);
    p += __shfl_xor(p, 2);
    p += __shfl_xor(p, 4);
    p += __shfl_xor(p, 8);
    p += __shfl_xor(p, 16);
    if (lane == 0) {
        float z = p + fcbv;
        out[node] = 1.0f / (1.0f + expf(-z));
    }
}

// ---------------- launch ----------------

extern "C" void kernel_launch(void* const* d_in, const int* in_sizes, int n_in,
                              void* d_out, int out_size, void* d_ws, size_t ws_size,
                              hipStream_t stream)
{
    const float* x   = (const float*)d_in[0];
    const int*   ei  = (const int*)d_in[1];
    const int*   src = ei;
    const int*   dst = ei + NEDGES;
    const float* w1l = (const float*)d_in[2];
    const float* w1r = (const float*)d_in[3];
    const float* b1  = (const float*)d_in[4];
    const float* g1  = (const float*)d_in[5];
    const float* bb1 = (const float*)d_in[6];
    const float* m1  = (const float*)d_in[7];
    const float* v1  = (const float*)d_in[8];
    const float* w2l = (const float*)d_in[9];
    const float* w2r = (const float*)d_in[10];
    const float* b2  = (const float*)d_in[11];
    const float* g2  = (const float*)d_in[12];
    const float* bb2 = (const float*)d_in[13];
    const float* m2  = (const float*)d_in[14];
    const float* v2  = (const float*)d_in[15];
    const float* w3l = (const float*)d_in[16];
    const float* w3r = (const float*)d_in[17];
    const float* b3  = (const float*)d_in[18];
    const float* fcw = (const float*)d_in[19];
    const float* fcb = (const float*)d_in[20];

    char* ws = (char*)d_ws;
    size_t off = 0;
    auto alloc = [&](size_t bytes) -> void* {
        void* p = ws + off;
        off += (bytes + 255) & ~(size_t)255;
        return p;
    };
    int*   offs   = (int*)alloc((size_t)(NNODES + 1) * 4);
    int*   bs     = (int*)alloc((size_t)NCHB * 4);
    int*   bse    = (int*)alloc((size_t)(NCHB + 1) * 4);
    int*   histT  = (int*)alloc((size_t)NCHB * NBLK * 4);
    float* deginv = (float*)alloc((size_t)NNODES * 4);
    int*   csr    = (int*)alloc((size_t)(NEDGES + 64) * 4);  // +64 pad
    bf16*  t2     = (bf16*)alloc((size_t)NNODES * 64 * 2);
    float* r2     = (float*)alloc((size_t)NNODES * 64 * 4);
    bf16*  t3     = (bf16*)alloc((size_t)NNODES * 32 * 2);
    float* r3     = (float*)alloc((size_t)NNODES * 32 * 4);
    int*   tmp    = (int*)r2;   // aliased: consumed by k_bucket before layer1 writes r2

    hipMemsetAsync(bs, 0, (size_t)NCHB * 4, stream);

    k_hist2<<<NBLK, 256, 0, stream>>>((const int4*)dst, histT, bs);
    k_scanbs<<<1, 512, 0, stream>>>(bs, bse, offs);
    k_scanhist<<<NCHB, 256, 0, stream>>>(histT, bse);
    k_scatter2<<<NBLK, 256, 0, stream>>>((const int4*)src, (const int4*)dst, histT, tmp);
    k_bucket<<<NCHB, 256, 0, stream>>>(tmp, bse, offs, deginv, csr);

    k_layer1<<<768, 256, 0, stream>>>(x, csr, offs, deginv,
                                      w1l, w1r, b1, g1, bb1, m1, v1,
                                      w2l, w2r, b2, g2, bb2, m2, v2,
                                      t2, r2);
    k_layer2<<<1024, 256, 0, stream>>>(t2, r2, csr, offs, deginv,
                                       w3l, w3r, b3, t3, r3);
    k_layer3<<<(NNODES + 3) / 4, 256, 0, stream>>>(t3, r3, csr, offs, deginv,
                                                   fcw, fcb, (float*)d_out);
}

// Round 8
// 405.052 us; speedup vs baseline: 3.7910x; 1.0533x over previous
//
#include <hip/hip_runtime.h>
#include <hip/hip_bf16.h>
#include <math.h>

#define NNODES 100000
#define NEDGES 3200000
constexpr int NCHB = (NNODES + 255) / 256; // 391 buckets of 256 nodes
constexpr int NBLK = 256;                  // partition blocks
constexpr int Q4PB = (NEDGES / 4) / NBLK;  // 3125 int4 per block (exact)

typedef __hip_bfloat16 bf16;
__device__ __forceinline__ bf16 f2b(float v) { return __float2bfloat16(v); }
__device__ __forceinline__ float lo2f(unsigned u) { return __uint_as_float(u << 16); }
__device__ __forceinline__ float hi2f(unsigned u) { return __uint_as_float(u & 0xffff0000u); }

// 8-way compile-time-tree select: returns a[c], c in 0..7
__device__ __forceinline__ float sel8(int c, float a0, float a1, float a2, float a3,
                                      float a4, float a5, float a6, float a7) {
    float b0 = (c & 1) ? a1 : a0, b2 = (c & 1) ? a3 : a2;
    float b4 = (c & 1) ? a5 : a4, b6 = (c & 1) ? a7 : a6;
    float c0 = (c & 2) ? b2 : b0, c4 = (c & 2) ? b6 : b4;
    return (c & 4) ? c4 : c0;
}

// ---------------- CSR build: one-pass radix partition by dst>>8 ----------------

__global__ __launch_bounds__(256) void k_hist2(const int4* __restrict__ dst4,
                                               int* __restrict__ histT,
                                               int* __restrict__ bs) {
    __shared__ int h[NCHB];
    int tid = threadIdx.x, blk = blockIdx.x;
    for (int i = tid; i < NCHB; i += 256) h[i] = 0;
    __syncthreads();
    int base = blk * Q4PB;
    for (int i = tid; i < Q4PB; i += 256) {
        int4 d = dst4[base + i];
        atomicAdd(&h[d.x >> 8], 1);
        atomicAdd(&h[d.y >> 8], 1);
        atomicAdd(&h[d.z >> 8], 1);
        atomicAdd(&h[d.w >> 8], 1);
    }
    __syncthreads();
    for (int i = tid; i < NCHB; i += 256) {
        int v = h[i];
        histT[i * NBLK + blk] = v;
        if (v) atomicAdd(&bs[i], v);   // no result needed -> pipelines
    }
}

__global__ void k_scanbs(const int* __restrict__ bs, int* __restrict__ bse,
                         int* __restrict__ offs) {
    __shared__ int s[512];
    int i = threadIdx.x;
    int v = (i < NCHB) ? bs[i] : 0;
    s[i] = v;
    __syncthreads();
    for (int off = 1; off < 512; off <<= 1) {
        int t = (i >= off) ? s[i - off] : 0;
        __syncthreads();
        s[i] += t;
        __syncthreads();
    }
    if (i < NCHB) bse[i] = s[i] - v;  // exclusive
    if (i == 0) { bse[NCHB] = NEDGES; offs[NNODES] = NEDGES; }
}

__global__ __launch_bounds__(256) void k_scanhist(int* __restrict__ histT,
                                                  const int* __restrict__ bse) {
    int b = blockIdx.x, tid = threadIdx.x;
    int lane = tid & 63, wid = tid >> 6;
    int d = histT[b * NBLK + tid];
    int v = d;  // inclusive wave scan
    { int t = __shfl_up(v, 1);  if (lane >= 1)  v += t; }
    { int t = __shfl_up(v, 2);  if (lane >= 2)  v += t; }
    { int t = __shfl_up(v, 4);  if (lane >= 4)  v += t; }
    { int t = __shfl_up(v, 8);  if (lane >= 8)  v += t; }
    { int t = __shfl_up(v, 16); if (lane >= 16) v += t; }
    { int t = __shfl_up(v, 32); if (lane >= 32) v += t; }
    __shared__ int ws[4];
    if (lane == 63) ws[wid] = v;
    __syncthreads();
    int woff = 0;
#pragma unroll
    for (int i = 0; i < 4; i++) woff += (i < wid) ? ws[i] : 0;
    histT[b * NBLK + tid] = bse[b] + woff + v - d;   // exclusive global base
}

__global__ __launch_bounds__(256) void k_scatter2(const int4* __restrict__ src4,
                                                  const int4* __restrict__ dst4,
                                                  const int* __restrict__ histT,
                                                  int* __restrict__ tmp) {
    __shared__ int cur[NCHB];
    int tid = threadIdx.x, blk = blockIdx.x;
    for (int i = tid; i < NCHB; i += 256) cur[i] = histT[i * NBLK + blk];
    __syncthreads();
    int base = blk * Q4PB;
    for (int i = tid; i < Q4PB; i += 256) {
        int4 s = src4[base + i];
        int4 d = dst4[base + i];
        int b, p;
        b = d.x >> 8; p = atomicAdd(&cur[b], 1); tmp[p] = ((d.x & 255) << 17) | s.x;
        b = d.y >> 8; p = atomicAdd(&cur[b], 1); tmp[p] = ((d.y & 255) << 17) | s.y;
        b = d.z >> 8; p = atomicAdd(&cur[b], 1); tmp[p] = ((d.z & 255) << 17) | s.z;
        b = d.w >> 8; p = atomicAdd(&cur[b], 1); tmp[p] = ((d.w & 255) << 17) | s.w;
    }
}

__global__ __launch_bounds__(256) void k_bucket(const int* __restrict__ tmp,
                                                const int* __restrict__ bse,
                                                int* __restrict__ offs,
                                                float* __restrict__ deginv,
                                                int* __restrict__ csr) {
    int b = blockIdx.x, tid = threadIdx.x;
    int lane = tid & 63, wid = tid >> 6;
    __shared__ int cnt[256], soff[256], ws[4];
    cnt[tid] = 0;
    __syncthreads();
    int s0 = bse[b], s1 = bse[b + 1];
    for (int i = s0 + tid; i < s1; i += 256) atomicAdd(&cnt[tmp[i] >> 17], 1);
    __syncthreads();
    int d = cnt[tid];
    int v = d;  // inclusive wave scan
    { int t = __shfl_up(v, 1);  if (lane >= 1)  v += t; }
    { int t = __shfl_up(v, 2);  if (lane >= 2)  v += t; }
    { int t = __shfl_up(v, 4);  if (lane >= 4)  v += t; }
    { int t = __shfl_up(v, 8);  if (lane >= 8)  v += t; }
    { int t = __shfl_up(v, 16); if (lane >= 16) v += t; }
    { int t = __shfl_up(v, 32); if (lane >= 32) v += t; }
    if (lane == 63) ws[wid] = v;
    __syncthreads();
    int woff = 0;
#pragma unroll
    for (int i = 0; i < 4; i++) woff += (i < wid) ? ws[i] : 0;
    int excl = woff + v - d;
    soff[tid] = excl;
    int node = b * 256 + tid;
    if (node < NNODES) {
        offs[node] = s0 + excl;
        deginv[node] = 1.0f / (float)max(d, 1);
    }
    cnt[tid] = 0;
    __syncthreads();
    for (int i = s0 + tid; i < s1; i += 256) {
        int e = tmp[i];
        int dl = e >> 17, src = e & 0x1FFFF;
        int slot = atomicAdd(&cnt[dl], 1);
        csr[s0 + soff[dl] + slot] = src;
    }
}

// ---- Layer 1 (1-wave blocks, weights truly in VGPRs) ----

__global__ __launch_bounds__(64, 1) void k_layer1(
    const float* __restrict__ x, const int* __restrict__ csr,
    const int* __restrict__ offs, const float* __restrict__ deginv,
    const float* __restrict__ w1l, const float* __restrict__ w1r,
    const float* __restrict__ b1,
    const float* __restrict__ g1, const float* __restrict__ bb1,
    const float* __restrict__ m1, const float* __restrict__ v1,
    const float* __restrict__ w2l, const float* __restrict__ w2r,
    const float* __restrict__ b2,
    const float* __restrict__ g2, const float* __restrict__ bb2,
    const float* __restrict__ m2, const float* __restrict__ v2,
    bf16* __restrict__ t2, float* __restrict__ r2)
{
    int lane = threadIdx.x;

    float k1 = g1[lane] * rsqrtf(v1[lane] + 1e-5f);
    float k2 = g2[lane] * rsqrtf(v2[lane] + 1e-5f);
    float c1 = (b1[lane] - m1[lane]) * k1 + bb1[lane];
    float c2 = (b2[lane] - m2[lane]) * k2 + bb2[lane];
    float w1lr[8], w1rr[8];
#pragma unroll
    for (int k = 0; k < 8; k++) {
        w1lr[k] = w1l[k * 64 + lane] * k1;
        w1rr[k] = w1r[k * 64 + lane] * k1;
    }
    float w2lr[64], w2rr[64];
#pragma unroll
    for (int k = 0; k < 64; k++) {
        w2lr[k] = w2l[k * 64 + lane] * k2;
        w2rr[k] = w2r[k * 64 + lane] * k2;
    }

    const float4* xv = (const float4*)x;
    for (int node = blockIdx.x; node < NNODES; node += gridDim.x) {
        int start = offs[node];
        int d = offs[node + 1] - start;
        int dl = min(d, 64);
        int c = csr[start + lane];                 // csr padded +64
        float xs = x[node * 8 + (lane & 7)];

        int fh = lane & 1;
        int g  = lane >> 1;
        int i0 = g, i1 = g + 32;
        int s0 = __shfl(c, i0), s1 = __shfl(c, i1);
        float m0 = (i0 < dl) ? 1.f : 0.f;
        float m1f = (i1 < dl) ? 1.f : 0.f;
        s0 = (i0 < dl) ? s0 : 0;
        s1 = (i1 < dl) ? s1 : 0;
        float4 w0 = xv[(size_t)s0 * 2 + fh];
        float4 w1 = xv[(size_t)s1 * 2 + fh];
        float ax = m0 * w0.x + m1f * w1.x;
        float ay = m0 * w0.y + m1f * w1.y;
        float az = m0 * w0.z + m1f * w1.z;
        float aw = m0 * w0.w + m1f * w1.w;
        for (int i = g + 64; i < d; i += 32) {     // rare tail
            int s = csr[start + i];
            float4 w = xv[(size_t)s * 2 + fh];
            ax += w.x; ay += w.y; az += w.z; aw += w.w;
        }
#define RED1(X) X += __shfl_xor(X, 2); X += __shfl_xor(X, 4); X += __shfl_xor(X, 8); \
                X += __shfl_xor(X, 16); X += __shfl_xor(X, 32);
        RED1(ax) RED1(ay) RED1(az) RED1(aw)
#undef RED1
        float di = deginv[node];
        ax *= di; ay *= di; az *= di; aw *= di;

        float h = c1;
#pragma unroll
        for (int k = 0; k < 8; k++) {
            float comp = ((k & 3) == 0) ? ax : ((k & 3) == 1) ? ay : ((k & 3) == 2) ? az : aw;
            float a  = __shfl(comp, k >> 2);
            float xr = __shfl(xs, k);
            h = fmaf(a, w1lr[k], fmaf(xr, w1rr[k], h));
        }
        h = fmaxf(h, 0.f);

        float tt = 0.f, rr = c2;
#pragma unroll
        for (int k = 0; k < 64; k++) {
            float hv = __shfl(h, k);
            tt = fmaf(hv, w2lr[k], tt);
            rr = fmaf(hv, w2rr[k], rr);
        }
        t2[(size_t)node * 64 + lane] = f2b(tt);
        r2[(size_t)node * 64 + lane] = rr;
    }
}

// ---- Layer 2 (1-wave blocks, w3 cols in VGPRs) ----

__global__ __launch_bounds__(64, 2) void k_layer2(
    const bf16* __restrict__ t2, const float* __restrict__ r2,
    const int* __restrict__ csr, const int* __restrict__ offs,
    const float* __restrict__ deginv,
    const float* __restrict__ w3l, const float* __restrict__ w3r,
    const float* __restrict__ b3,
    bf16* __restrict__ t3, float* __restrict__ r3)
{
    int lane = threadIdx.x;
    int j = lane & 31, half = lane >> 5;

    const float* wp = half ? w3r : w3l;
    float wcol[64];
#pragma unroll
    for (int k = 0; k < 64; k++) wcol[k] = wp[k * 32 + j];
    float b3v = half ? b3[j] : 0.f;

    const uint4* t2v = (const uint4*)t2;
    for (int node = blockIdx.x; node < NNODES; node += gridDim.x) {
        int start = offs[node];
        int d = offs[node + 1] - start;
        int dl = min(d, 64);
        int c = csr[start + lane];
        float r2v = r2[(size_t)node * 64 + lane];

        int fq = lane & 7;
        int g  = lane >> 3;
        int   si[8];
        float mk[8];
#pragma unroll
        for (int t = 0; t < 8; t++) {
            int i = g + 8 * t;
            int s = __shfl(c, i);
            mk[t] = (i < dl) ? 1.f : 0.f;
            si[t] = (i < dl) ? s : 0;
        }
        uint4 w0 = t2v[(size_t)si[0] * 8 + fq];
        uint4 w1 = t2v[(size_t)si[1] * 8 + fq];
        uint4 w2 = t2v[(size_t)si[2] * 8 + fq];
        uint4 w3 = t2v[(size_t)si[3] * 8 + fq];
        uint4 w4 = t2v[(size_t)si[4] * 8 + fq];
        uint4 w5 = t2v[(size_t)si[5] * 8 + fq];
        uint4 w6 = t2v[(size_t)si[6] * 8 + fq];
        uint4 w7 = t2v[(size_t)si[7] * 8 + fq];

        float a0 = 0, a1 = 0, a2 = 0, a3 = 0, a4 = 0, a5 = 0, a6 = 0, a7 = 0;
#define CONS(W, M) \
        a0 = fmaf(M, lo2f(W.x), a0); a1 = fmaf(M, hi2f(W.x), a1); \
        a2 = fmaf(M, lo2f(W.y), a2); a3 = fmaf(M, hi2f(W.y), a3); \
        a4 = fmaf(M, lo2f(W.z), a4); a5 = fmaf(M, hi2f(W.z), a5); \
        a6 = fmaf(M, lo2f(W.w), a6); a7 = fmaf(M, hi2f(W.w), a7);
        CONS(w0, mk[0]) CONS(w1, mk[1]) CONS(w2, mk[2]) CONS(w3, mk[3])
        CONS(w4, mk[4]) CONS(w5, mk[5]) CONS(w6, mk[6]) CONS(w7, mk[7])
        for (int i = g + 64; i < d; i += 8) {
            int s = csr[start + i];
            uint4 w = t2v[(size_t)s * 8 + fq];
            CONS(w, 1.f)
        }
#undef CONS
#define RED2(X) X += __shfl_xor(X, 8); X += __shfl_xor(X, 16); X += __shfl_xor(X, 32);
        RED2(a0) RED2(a1) RED2(a2) RED2(a3) RED2(a4) RED2(a5) RED2(a6) RED2(a7)
#undef RED2
        float u = sel8(lane >> 3, a0, a1, a2, a3, a4, a5, a6, a7);
        int srcl = ((lane & 7) << 3) | (lane >> 3);
        float v = __shfl(u, srcl);

        float h2 = fmaxf(v * deginv[node] + r2v, 0.f);

        float acc = b3v;
#pragma unroll
        for (int k = 0; k < 64; k++) {
            float hv = __shfl(h2, k);
            acc = fmaf(hv, wcol[k], acc);
        }
        if (half == 0) t3[(size_t)node * 32 + j] = f2b(acc);
        else           r3[(size_t)node * 32 + j] = acc;
    }
}

// ---- Layer 3: gather t3 (bf16) -> relu(agg+r3) -> fc -> sigmoid ----

__global__ __launch_bounds__(256) void k_layer3(
    const bf16* __restrict__ t3, const float* __restrict__ r3,
    const int* __restrict__ csr, const int* __restrict__ offs,
    const float* __restrict__ deginv,
    const float* __restrict__ fcw, const float* __restrict__ fcb,
    float* __restrict__ out)
{
    int tid = threadIdx.x;
    int lane = tid & 63;
    int node = blockIdx.x * 4 + (tid >> 6);
    if (node >= NNODES) return;

    int o = lane & 31;
    float fcwv = fcw[o];
    float fcbv = fcb[0];

    int start = offs[node];
    int d = offs[node + 1] - start;
    int dl = min(d, 64);
    int c = csr[start + lane];
    float r3v = r3[(size_t)node * 32 + o];

    int fq = lane & 3;
    int g  = lane >> 2;
    const uint4* t3v = (const uint4*)t3;

    int   si[4];
    float mk[4];
#pragma unroll
    for (int t = 0; t < 4; t++) {
        int i = g + 16 * t;
        int s = __shfl(c, i);
        mk[t] = (i < dl) ? 1.f : 0.f;
        si[t] = (i < dl) ? s : 0;
    }
    uint4 w0 = t3v[(size_t)si[0] * 4 + fq];
    uint4 w1 = t3v[(size_t)si[1] * 4 + fq];
    uint4 w2 = t3v[(size_t)si[2] * 4 + fq];
    uint4 w3 = t3v[(size_t)si[3] * 4 + fq];

    float a0 = 0, a1 = 0, a2 = 0, a3 = 0, a4 = 0, a5 = 0, a6 = 0, a7 = 0;
#define CONS(W, M) \
    a0 = fmaf(M, lo2f(W.x), a0); a1 = fmaf(M, hi2f(W.x), a1); \
    a2 = fmaf(M, lo2f(W.y), a2); a3 = fmaf(M, hi2f(W.y), a3); \
    a4 = fmaf(M, lo2f(W.z), a4); a5 = fmaf(M, hi2f(W.z), a5); \
    a6 = fmaf(M, lo2f(W.w), a6); a7 = fmaf(M, hi2f(W.w), a7);
    CONS(w0, mk[0]) CONS(w1, mk[1]) CONS(w2, mk[2]) CONS(w3, mk[3])
    for (int i = g + 64; i < d; i += 16) {
        int s = csr[start + i];
        uint4 w = t3v[(size_t)s * 4 + fq];
        CONS(w, 1.f)
    }
#undef CONS
#define RED3(X) X += __shfl_xor(X, 4); X += __shfl_xor(X, 8); X += __shfl_xor(X, 16); X += __shfl_xor(X, 32);
    RED3(a0) RED3(a1) RED3(a2) RED3(a3) RED3(a4) RED3(a5) RED3(a6) RED3(a7)
#undef RED3
    float u = sel8((lane >> 2) & 7, a0, a1, a2, a3, a4, a5, a6, a7);
    int srcl = ((lane & 7) << 2) | ((lane >> 3) & 3);
    float v = __shfl(u, srcl);

    float h3 = fmaxf(v * deginv[node] + r3v, 0.f);

    float p = h3 * fcwv;
    p += __shfl_xor(p, 1);
    p += __shfl_xor(p, 2);
    p += __shfl_xor(p, 4);
    p += __shfl_xor(p, 8);
    p += __shfl_xor(p, 16);
    if (lane == 0) {
        float z = p + fcbv;
        out[node] = 1.0f / (1.0f + expf(-z));
    }
}

// ---------------- launch ----------------

extern "C" void kernel_launch(void* const* d_in, const int* in_sizes, int n_in,
                              void* d_out, int out_size, void* d_ws, size_t ws_size,
                              hipStream_t stream)
{
    const float* x   = (const float*)d_in[0];
    const int*   ei  = (const int*)d_in[1];
    const int*   src = ei;
    const int*   dst = ei + NEDGES;
    const float* w1l = (const float*)d_in[2];
    const float* w1r = (const float*)d_in[3];
    const float* b1  = (const float*)d_in[4];
    const float* g1  = (const float*)d_in[5];
    const float* bb1 = (const float*)d_in[6];
    const float* m1  = (const float*)d_in[7];
    const float* v1  = (const float*)d_in[8];
    const float* w2l = (const float*)d_in[9];
    const float* w2r = (const float*)d_in[10];
    const float* b2  = (const float*)d_in[11];
    const float* g2  = (const float*)d_in[12];
    const float* bb2 = (const float*)d_in[13];
    const float* m2  = (const float*)d_in[14];
    const float* v2  = (const float*)d_in[15];
    const float* w3l = (const float*)d_in[16];
    const float* w3r = (const float*)d_in[17];
    const float* b3  = (const float*)d_in[18];
    const float* fcw = (const float*)d_in[19];
    const float* fcb = (const float*)d_in[20];

    char* ws = (char*)d_ws;
    size_t off = 0;
    auto alloc = [&](size_t bytes) -> void* {
        void* p = ws + off;
        off += (bytes + 255) & ~(size_t)255;
        return p;
    };
    int*   offs   = (int*)alloc((size_t)(NNODES + 1) * 4);
    int*   bs     = (int*)alloc((size_t)NCHB * 4);
    int*   bse    = (int*)alloc((size_t)(NCHB + 1) * 4);
    int*   histT  = (int*)alloc((size_t)NCHB * NBLK * 4);
    float* deginv = (float*)alloc((size_t)NNODES * 4);
    int*   csr    = (int*)alloc((size_t)(NEDGES + 64) * 4);  // +64 pad
    bf16*  t2     = (bf16*)alloc((size_t)NNODES * 64 * 2);
    float* r2     = (float*)alloc((size_t)NNODES * 64 * 4);
    bf16*  t3     = (bf16*)alloc((size_t)NNODES * 32 * 2);
    float* r3     = (float*)alloc((size_t)NNODES * 32 * 4);
    int*   tmp    = (int*)r2;   // aliased: consumed by k_bucket before layer1 writes r2

    hipMemsetAsync(bs, 0, (size_t)NCHB * 4, stream);

    k_hist2<<<NBLK, 256, 0, stream>>>((const int4*)dst, histT, bs);
    k_scanbs<<<1, 512, 0, stream>>>(bs, bse, offs);
    k_scanhist<<<NCHB, 256, 0, stream>>>(histT, bse);
    k_scatter2<<<NBLK, 256, 0, stream>>>((const int4*)src, (const int4*)dst, histT, tmp);
    k_bucket<<<NCHB, 256, 0, stream>>>(tmp, bse, offs, deginv, csr);

    k_layer1<<<2048, 64, 0, stream>>>(x, csr, offs, deginv,
                                      w1l, w1r, b1, g1, bb1, m1, v1,
                                      w2l, w2r, b2, g2, bb2, m2, v2,
                                      t2, r2);
    k_layer2<<<3072, 64, 0, stream>>>(t2, r2, csr, offs, deginv,
                                      w3l, w3r, b3, t3, r3);
    k_layer3<<<(NNODES + 3) / 4, 256, 0, stream>>>(t3, r3, csr, offs, deginv,
                                                   fcw, fcb, (float*)d_out);
}